// Round 12
// baseline (93.059 us; speedup 1.0000x reference)
//
#include <hip/hip_runtime.h>

#define EPS 1e-5f

typedef float f32x4 __attribute__((ext_vector_type(4)));
typedef short bf16x8 __attribute__((ext_vector_type(8)));

__device__ __forceinline__ unsigned short f2bf(float f) {
  unsigned int u = __builtin_bit_cast(unsigned int, f);
  u = (u + 0x7FFFu + ((u >> 16) & 1u)) >> 16;
  return (unsigned short)u;
}
__device__ __forceinline__ float bf2f(unsigned short h) {
  unsigned int u = ((unsigned int)h) << 16;
  return __builtin_bit_cast(float, u);
}
// HW packed f32->bf16 RNE (bit-identical to f2bf; verified r10/r11)
__device__ __forceinline__ unsigned int cvt2(float a, float b) {
  unsigned int r;
  asm("v_cvt_pk_bf16_f32 %0, %1, %2" : "=v"(r) : "v"(a), "v"(b));
  return r;
}

// ---------------------------------------------------------------------------
// Prep: w1f f32 [c][m] (r0-verified), w2f MFMA A-fragments (r7-verified),
// folded betas.
// ---------------------------------------------------------------------------
__global__ __launch_bounds__(256) void k_prep(
    const float* __restrict__ w1, const float* __restrict__ b1,
    const float* __restrict__ g1, const float* __restrict__ be1,
    const float* __restrict__ m1, const float* __restrict__ v1,
    const float* __restrict__ w2, const float* __restrict__ b2,
    const float* __restrict__ g2, const float* __restrict__ be2,
    const float* __restrict__ m2, const float* __restrict__ v2,
    float* __restrict__ beta1, float* __restrict__ beta2,
    float* __restrict__ w1f, unsigned short* __restrict__ w2f)
{
  int t = blockIdx.x * 256 + threadIdx.x;
  if (t < 139264) {   // w2 fragments: 17 ks * 16 ct * 64 lanes * 8
    int j = t & 7, l = (t >> 3) & 63, g = t >> 9;
    int ct = g & 15, ks = g >> 4;
    int k = ks * 32 + (l >> 4) * 8 + j;
    int ch = ct * 16 + (l & 15);
    float val = 0.f;
    if (k < 528) {
      float s2 = g2[ch] * rsqrtf(v2[ch] + EPS);
      val = w2[ch * 528 + k] * s2;
    }
    w2f[t] = f2bf(val);
  }
  if (t < 8192) {     // w1f[c][m] = w1[m][c] * s1[m]  (r0 layout)
    int c = t >> 5, m = t & 31;
    float s1 = g1[m] * rsqrtf(v1[m] + EPS);
    w1f[t] = w1[m * 256 + c] * s1;
  }
  if (t < 32) {
    float s1 = g1[t] * rsqrtf(v1[t] + EPS);
    beta1[t] = (b1[t] - m1[t]) * s1 + be1[t];
  }
  if (t < 256) {
    float s2 = g2[t] * rsqrtf(v2[t] + EPS);
    beta2[t] = (b2[t] - m2[t]) * s2 + be2[t];
  }
}

// ---------------------------------------------------------------------------
// k_l1: streaming layer-1.  Thread = 1 pixel; loop c ascending (r0 order);
// coalesced 256-B wave reads of x; wave-uniform w1f rows (SGPR FMAs);
// y = relu(acc+beta1) -> bf16 [px][32] (64 B contiguous per px).
// ZERO barriers, ZERO LDS.  1024 blocks x 64 thr.
// ---------------------------------------------------------------------------
__global__ __launch_bounds__(64) void k_l1(
    const float* __restrict__ x, const float* __restrict__ w1f,
    const float* __restrict__ beta1, unsigned short* __restrict__ yws)
{
  int px = blockIdx.x * 64 + threadIdx.x;
  int b = px >> 12, hw = px & 4095;
  const float* xb = x + ((size_t)b << 20) + hw;

  float acc[32];
#pragma unroll
  for (int m = 0; m < 32; ++m) acc[m] = 0.f;

#pragma unroll 4
  for (int c = 0; c < 256; ++c) {
    float xv = xb[(size_t)c * 4096];
    const float* wr = &w1f[c * 32];
#pragma unroll
    for (int m = 0; m < 32; ++m) acc[m] = fmaf(xv, wr[m], acc[m]);
  }

  unsigned int ow[16];
#pragma unroll
  for (int m = 0; m < 16; ++m) {
    float a  = fmaxf(acc[2 * m]     + beta1[2 * m],     0.f);
    float bv = fmaxf(acc[2 * m + 1] + beta1[2 * m + 1], 0.f);
    ow[m] = cvt2(a, bv);
  }
  uint4* dst = (uint4*)(yws + (size_t)px * 32);
#pragma unroll
  for (int q = 0; q < 4; ++q)
    dst[q] = make_uint4(ow[4 * q], ow[4 * q + 1], ow[4 * q + 2], ow[4 * q + 3]);
}

// Write diag I (reference order, len 32-I at base(I)) from register y-row.
template<int I>
__device__ __forceinline__ void do_diag(const float* __restrict__ y,
                                        unsigned short* __restrict__ pr)
{
  constexpr int L = 32 - I;
  constexpr int base = 32 * I - (I * (I - 1)) / 2;
  float p[L];
#pragma unroll
  for (int j = 0; j < L; ++j) p[j] = y[I + j] * y[j];
  constexpr int s = (base & 1) ? 1 : 0;
  if constexpr (s != 0) pr[base] = f2bf(p[0]);
#pragma unroll
  for (int j = s; j + 1 < L; j += 2)
    *(unsigned int*)&pr[base + j] = cvt2(p[j], p[j + 1]);
  if constexpr (((L - s) & 1) != 0) pr[base + L - 1] = f2bf(p[L - 1]);
}

// Balanced set (r4/r7-verified): diags {S, 31-S, S+8, 23-S} = 66 products.
template<int S>
__device__ __forceinline__ void do_set(const float* __restrict__ y,
                                       unsigned short* __restrict__ pr)
{
  do_diag<S>(y, pr);
  do_diag<31 - S>(y, pr);
  do_diag<S + 8>(y, pr);
  do_diag<23 - S>(y, pr);
}

// ---------------------------------------------------------------------------
// k_l2: products + layer-2.  32-px blocks (2048, XCD-swizzled), 4 blocks/CU.
//  P2: y-row read from GLOBAL (64 B bf16, L2/L3-hot) -> f32 regs;
//      verified do_set partition -> pk (stride 548); ONE barrier.
//  P3: r7's 17 ks x 4 ct x 2 pt MFMA + BN/relu + coalesced stores.
// LDS: pk 35072 B only.
// ---------------------------------------------------------------------------
__global__ __launch_bounds__(256, 4) void k_l2(
    const unsigned short* __restrict__ yws, const unsigned short* __restrict__ w2f,
    const float* __restrict__ beta2, float* __restrict__ out)
{
  __shared__ __align__(16) unsigned short pk[32 * 548];
  int tid = threadIdx.x;
  int wv = tid >> 6, lane = tid & 63;
  int l15 = lane & 15, l4 = lane >> 4;
  int g = blockIdx.x;
  int orig = ((g & 7) << 8) + (g >> 3);   // bijective XCD swizzle (2048%8==0)
  int pb = orig * 32;
  int b = pb >> 12, hw0 = pb & 4095;

  // ---- P2: global y-row -> f32 regs; products -> pk (reference order)
  {
    int px2 = tid & 31, set = tid >> 5;
    const uint4* y4 = (const uint4*)(yws + (size_t)(pb + px2) * 32);
    float y[32];
#pragma unroll
    for (int qq = 0; qq < 4; ++qq) {
      uint4 v = y4[qq];
      unsigned int ua[4] = {v.x, v.y, v.z, v.w};
#pragma unroll
      for (int w = 0; w < 4; ++w) {
        y[qq * 8 + 2 * w]     = bf2f((unsigned short)(ua[w] & 0xFFFFu));
        y[qq * 8 + 2 * w + 1] = bf2f((unsigned short)(ua[w] >> 16));
      }
    }
    unsigned short* pr = &pk[px2 * 548];
    switch (set) {
      case 0: do_set<0>(y, pr); break;
      case 1: do_set<1>(y, pr); break;
      case 2: do_set<2>(y, pr); break;
      case 3: do_set<3>(y, pr); break;
      case 4: do_set<4>(y, pr); break;
      case 5: do_set<5>(y, pr); break;
      case 6: do_set<6>(y, pr); break;
      default: do_set<7>(y, pr); break;
    }
    if (set < 4) {   // zero K-pad slots 528..543
      *(unsigned int*)&pr[528 + set * 4] = 0u;
      *(unsigned int*)&pr[530 + set * 4] = 0u;
    }
  }

  float bet[4][4];
#pragma unroll
  for (int ctl = 0; ctl < 4; ++ctl)
#pragma unroll
    for (int r = 0; r < 4; ++r)
      bet[ctl][r] = beta2[(wv * 4 + ctl) * 16 + l4 * 4 + r];

  __syncthreads();   // pk ready (the only barrier)

  // ---- P3 (r7-verified): wave owns ct = wv*4..wv*4+3, pt = 0..1.
  f32x4 acc[2][4];
#pragma unroll
  for (int a = 0; a < 2; ++a)
#pragma unroll
    for (int c = 0; c < 4; ++c)
      acc[a][c] = (f32x4){0.f, 0.f, 0.f, 0.f};

  const uint4* w2f4 = (const uint4*)w2f;
#pragma unroll
  for (int ks = 0; ks < 17; ++ks) {
    union { uint4 q; bf16x8 v; } A[4], B[2];
#pragma unroll
    for (int ctl = 0; ctl < 4; ++ctl)
      A[ctl].q = w2f4[(ks * 16 + wv * 4 + ctl) * 64 + lane];
#pragma unroll
    for (int pt = 0; pt < 2; ++pt) {
      const unsigned short* src = &pk[(pt * 16 + l15) * 548 + ks * 32 + l4 * 8];
      uint2 lo = *(const uint2*)src;
      uint2 hi = *(const uint2*)(src + 4);
      B[pt].q = make_uint4(lo.x, lo.y, hi.x, hi.y);
    }
#pragma unroll
    for (int pt = 0; pt < 2; ++pt)
#pragma unroll
      for (int ctl = 0; ctl < 4; ++ctl)
        acc[pt][ctl] = __builtin_amdgcn_mfma_f32_16x16x32_bf16(
            A[ctl].v, B[pt].v, acc[pt][ctl], 0, 0, 0);
  }

  // ---- epilogue: BN fold + relu, coalesced stores
#pragma unroll
  for (int pt = 0; pt < 2; ++pt) {
    int hw = hw0 + pt * 16 + l15;
#pragma unroll
    for (int ctl = 0; ctl < 4; ++ctl) {
      int ch = (wv * 4 + ctl) * 16 + l4 * 4;
#pragma unroll
      for (int r = 0; r < 4; ++r) {
        float v = fmaxf(acc[pt][ctl][r] + bet[ctl][r], 0.f);
        out[(((size_t)b * 256 + (ch + r)) << 12) + hw] = v;
      }
    }
  }
}

// ---------------------------------------------------------------------------
extern "C" void kernel_launch(void* const* d_in, const int* in_sizes, int n_in,
                              void* d_out, int out_size, void* d_ws, size_t ws_size,
                              hipStream_t stream)
{
  const float* x   = (const float*)d_in[0];
  const float* w1  = (const float*)d_in[1];
  const float* b1  = (const float*)d_in[2];
  const float* g1  = (const float*)d_in[3];
  const float* be1 = (const float*)d_in[4];
  const float* m1  = (const float*)d_in[5];
  const float* v1  = (const float*)d_in[6];
  const float* w2  = (const float*)d_in[7];
  const float* b2  = (const float*)d_in[8];
  const float* g2  = (const float*)d_in[9];
  const float* be2 = (const float*)d_in[10];
  const float* m2  = (const float*)d_in[11];
  const float* v2  = (const float*)d_in[12];

  char* ws = (char*)d_ws;
  float*          beta1 = (float*)(ws);                   // 128 B
  float*          beta2 = (float*)(ws + 128);             // 1024 B
  float*          w1f   = (float*)(ws + 1152);            // 32768 B
  unsigned short* w2f   = (unsigned short*)(ws + 33920);  // 278528 B
  unsigned short* yws   = (unsigned short*)(ws + 312448); // 4 MB
  float* out = (float*)d_out;

  k_prep<<<dim3(544), dim3(256), 0, stream>>>(
      w1, b1, g1, be1, m1, v1, w2, b2, g2, be2, m2, v2, beta1, beta2, w1f, w2f);
  k_l1<<<dim3(1024), dim3(64), 0, stream>>>(x, w1f, beta1, yws);
  k_l2<<<dim3(2048), dim3(256), 0, stream>>>(yws, w2f, beta2, out);
}

// Round 13
// 51.303 us; speedup vs baseline: 1.8139x; 1.8139x over previous
//
#include <hip/hip_runtime.h>

#define EPS 1e-5f

typedef float f32x4 __attribute__((ext_vector_type(4)));
typedef short bf16x8 __attribute__((ext_vector_type(8)));

__device__ __forceinline__ unsigned short f2bf(float f) {
  unsigned int u = __builtin_bit_cast(unsigned int, f);
  u = (u + 0x7FFFu + ((u >> 16) & 1u)) >> 16;
  return (unsigned short)u;
}
__device__ __forceinline__ float bf2f(unsigned short h) {
  unsigned int u = ((unsigned int)h) << 16;
  return __builtin_bit_cast(float, u);
}
// HW packed f32->bf16 RNE (bit-identical to f2bf; verified r10/r11/r12)
__device__ __forceinline__ unsigned int cvt2(float a, float b) {
  unsigned int r;
  asm("v_cvt_pk_bf16_f32 %0, %1, %2" : "=v"(r) : "v"(a), "v"(b));
  return r;
}

// ---------------------------------------------------------------------------
// Prep (r7-verified): w1b + w2f MFMA A-fragments (bf16, reference k-order),
// folded betas.  idx = ((ks*CT + ct)*64 + lane)*8 + j
//   <-> A[ch = ct*16 + (lane&15)][k = ks*32 + (lane>>4)*8 + j]
// ---------------------------------------------------------------------------
__global__ __launch_bounds__(256) void k_prep(
    const float* __restrict__ w1, const float* __restrict__ b1,
    const float* __restrict__ g1, const float* __restrict__ be1,
    const float* __restrict__ m1, const float* __restrict__ v1,
    const float* __restrict__ w2, const float* __restrict__ b2,
    const float* __restrict__ g2, const float* __restrict__ be2,
    const float* __restrict__ m2, const float* __restrict__ v2,
    float* __restrict__ beta1, float* __restrict__ beta2,
    unsigned short* __restrict__ w1b, unsigned short* __restrict__ w2f)
{
  int t = blockIdx.x * 256 + threadIdx.x;
  if (t < 139264) {   // w2 fragments: 17 ks * 16 ct * 64 lanes * 8
    int j = t & 7, l = (t >> 3) & 63, g = t >> 9;
    int ct = g & 15, ks = g >> 4;
    int k = ks * 32 + (l >> 4) * 8 + j;
    int ch = ct * 16 + (l & 15);
    float val = 0.f;
    if (k < 528) {
      float s2 = g2[ch] * rsqrtf(v2[ch] + EPS);
      val = w2[ch * 528 + k] * s2;
    }
    w2f[t] = f2bf(val);
  }
  if (t < 8192) {     // w1 fragments: 8 ks * 2 ct * 64 lanes * 8
    int j = t & 7, l = (t >> 3) & 63, g = t >> 9;
    int ct = g & 1, ks = g >> 1;
    int c = ks * 32 + (l >> 4) * 8 + j;
    int m = ct * 16 + (l & 15);
    float s1 = g1[m] * rsqrtf(v1[m] + EPS);
    w1b[t] = f2bf(w1[m * 256 + c] * s1);
  }
  if (t < 32) {
    float s1 = g1[t] * rsqrtf(v1[t] + EPS);
    beta1[t] = (b1[t] - m1[t]) * s1 + be1[t];
  }
  if (t < 256) {
    float s2 = g2[t] * rsqrtf(v2[t] + EPS);
    beta2[t] = (b2[t] - m2[t]) * s2 + be2[t];
  }
}

// ---------------------------------------------------------------------------
// k_l1: layer-1 only (r7's verified P0+P1), 32-px blocks, 2048 blocks.
// LDS = xt 17664 B only -> ~8 blocks/CU (32 waves/CU).  y -> global bf16
// yws[px][32] (r12-verified format/values).
// ---------------------------------------------------------------------------
__global__ __launch_bounds__(256) void k_l1(
    const float* __restrict__ x, const unsigned short* __restrict__ w1b,
    const float* __restrict__ beta1, unsigned short* __restrict__ yws)
{
  __shared__ __align__(16) unsigned short xt[32 * 276];
  int tid = threadIdx.x;
  int wv = tid >> 6, lane = tid & 63;
  int l15 = lane & 15, l4 = lane >> 4;
  int g = blockIdx.x;
  int orig = ((g & 7) << 8) + (g >> 3);   // bijective XCD swizzle (2048%8==0)
  int pb = orig * 32;
  int b = pb >> 12, hw0 = pb & 4095;
  const float* xb = x + ((size_t)b << 20) + hw0;

  // ---- P0 (r7): stage x -> bf16 transposed tile (row = px, stride 276)
  {
    int q = tid & 7;          // px quad (4*q .. 4*q+3)
    int cg = tid >> 3;        // channel-quad index within pass (0..31)
#pragma unroll
    for (int pass = 0; pass < 2; ++pass) {
      int c4 = cg + pass * 32;    // ch = 4*c4 + i
      float4 v[4];
#pragma unroll
      for (int i = 0; i < 4; ++i)
        v[i] = *(const float4*)&xb[(size_t)(4 * c4 + i) * 4096 + 4 * q];
#pragma unroll
      for (int s = 0; s < 4; ++s) {
        const float* e0 = (const float*)&v[0];
        const float* e1 = (const float*)&v[1];
        const float* e2 = (const float*)&v[2];
        const float* e3 = (const float*)&v[3];
        *(uint2*)&xt[(4 * q + s) * 276 + 4 * c4] =
            make_uint2(cvt2(e0[s], e1[s]), cvt2(e2[s], e3[s]));
      }
    }
  }
  __syncthreads();

  // ---- P1 (r7): layer1 MFMA; wave = (pxt = wv&1, mt = wv>>1) 16x16 tile
  {
    int pxt = wv & 1, mt = wv >> 1;
    int px = pxt * 16 + l15;
    f32x4 acc1 = (f32x4){0.f, 0.f, 0.f, 0.f};
    const uint4* w1b4 = (const uint4*)w1b;
#pragma unroll
    for (int ks = 0; ks < 8; ++ks) {
      union { uint4 q; bf16x8 v; } A, B;
      A.q = w1b4[(ks * 2 + mt) * 64 + lane];
      const unsigned short* s = &xt[px * 276 + ks * 32 + l4 * 8];
      uint2 lo = *(const uint2*)s;
      uint2 hi = *(const uint2*)(s + 4);
      B.q = make_uint4(lo.x, lo.y, hi.x, hi.y);
      acc1 = __builtin_amdgcn_mfma_f32_16x16x32_bf16(A.v, B.v, acc1, 0, 0, 0);
    }
    int m0 = mt * 16 + l4 * 4;
    float v0 = fmaxf(acc1[0] + beta1[m0 + 0], 0.f);
    float v1 = fmaxf(acc1[1] + beta1[m0 + 1], 0.f);
    float v2 = fmaxf(acc1[2] + beta1[m0 + 2], 0.f);
    float v3 = fmaxf(acc1[3] + beta1[m0 + 3], 0.f);
    *(uint2*)&yws[(size_t)(pb + px) * 32 + m0] =
        make_uint2(cvt2(v0, v1), cvt2(v2, v3));
  }
}

// Write diag I (reference order, len 32-I at base(I)) from register y-row.
template<int I>
__device__ __forceinline__ void do_diag(const float* __restrict__ y,
                                        unsigned short* __restrict__ pr)
{
  constexpr int L = 32 - I;
  constexpr int base = 32 * I - (I * (I - 1)) / 2;
  float p[L];
#pragma unroll
  for (int j = 0; j < L; ++j) p[j] = y[I + j] * y[j];
  constexpr int s = (base & 1) ? 1 : 0;
  if constexpr (s != 0) pr[base] = f2bf(p[0]);
#pragma unroll
  for (int j = s; j + 1 < L; j += 2)
    *(unsigned int*)&pr[base + j] = cvt2(p[j], p[j + 1]);
  if constexpr (((L - s) & 1) != 0) pr[base + L - 1] = f2bf(p[L - 1]);
}

// Balanced set (r4/r7/r12-verified): diags {S, 31-S, S+8, 23-S} = 66 products.
template<int S>
__device__ __forceinline__ void do_set(const float* __restrict__ y,
                                       unsigned short* __restrict__ pr)
{
  do_diag<S>(y, pr);
  do_diag<31 - S>(y, pr);
  do_diag<S + 8>(y, pr);
  do_diag<23 - S>(y, pr);
}

// One 32-px slice of P2 (r12-verified global-y path): 256 threads <-> 32 px
// x 8 sets.  tid256 in [0,256).
__device__ __forceinline__ void p2_slice(const unsigned short* __restrict__ yws,
                                         int pb, int px_base,
                                         unsigned short* __restrict__ pk,
                                         int tid256)
{
  int px2 = tid256 & 31, set = tid256 >> 5;
  int pxl = px_base + px2;
  const uint4* y4 = (const uint4*)(yws + (size_t)(pb + pxl) * 32);
  float y[32];
#pragma unroll
  for (int qq = 0; qq < 4; ++qq) {
    uint4 v = y4[qq];
    unsigned int ua[4] = {v.x, v.y, v.z, v.w};
#pragma unroll
    for (int w = 0; w < 4; ++w) {
      y[qq * 8 + 2 * w]     = bf2f((unsigned short)(ua[w] & 0xFFFFu));
      y[qq * 8 + 2 * w + 1] = bf2f((unsigned short)(ua[w] >> 16));
    }
  }
  unsigned short* pr = &pk[pxl * 548];
  switch (set) {
    case 0: do_set<0>(y, pr); break;
    case 1: do_set<1>(y, pr); break;
    case 2: do_set<2>(y, pr); break;
    case 3: do_set<3>(y, pr); break;
    case 4: do_set<4>(y, pr); break;
    case 5: do_set<5>(y, pr); break;
    case 6: do_set<6>(y, pr); break;
    default: do_set<7>(y, pr); break;
  }
  if (set < 4) {   // zero K-pad slots 528..543
    *(unsigned int*)&pr[528 + set * 4] = 0u;
    *(unsigned int*)&pr[530 + set * 4] = 0u;
  }
}

// ---------------------------------------------------------------------------
// k_l2: products + layer-2 at P=128 px/block (512 blocks x 512 thr).
// A-fragment L2 traffic: 512 x 272 KB = 139 MB (~4 us) vs 557 MB at P=32.
//  P2: 4 x verified 32-px slices (2 per 256-thread half)      (one barrier)
//  P3: 17 ks; wave owns ct = {2wv, 2wv+1}, pt = 0..7 ->
//      2 A-loads + 8 B ds_reads + 16 MFMA per ks; BN/relu; stores.
// LDS: pk 128 x 548 x 2B = 140288 B -> 1 block/CU, 8 waves.
// ---------------------------------------------------------------------------
__global__ __launch_bounds__(512) void k_l2(
    const unsigned short* __restrict__ yws, const unsigned short* __restrict__ w2f,
    const float* __restrict__ beta2, float* __restrict__ out)
{
  __shared__ __align__(16) unsigned short pk[128 * 548];
  int tid = threadIdx.x;
  int wv = tid >> 6, lane = tid & 63;
  int l15 = lane & 15, l4 = lane >> 4;
  int g = blockIdx.x;
  int orig = ((g & 7) << 6) + (g >> 3);   // bijective XCD swizzle (512%8==0)
  int pb = orig * 128;
  int b = pb >> 12, hw0 = pb & 4095;

  // ---- P2: 128 px = 4 verified 32-px slices; 512 threads = 2 slice-units
  {
    int half = tid >> 8;          // 0 or 1
    int tid256 = tid & 255;
    p2_slice(yws, pb, half * 32, pk, tid256);
    p2_slice(yws, pb, (2 + half) * 32, pk, tid256);
  }

  float bet[2][4];
#pragma unroll
  for (int ci = 0; ci < 2; ++ci)
#pragma unroll
    for (int r = 0; r < 4; ++r)
      bet[ci][r] = beta2[(wv * 2 + ci) * 16 + l4 * 4 + r];

  __syncthreads();   // pk ready (the only barrier)

  // ---- P3: wave owns ct = {2wv, 2wv+1}, pt = 0..7.
  f32x4 acc[8][2];
#pragma unroll
  for (int a = 0; a < 8; ++a)
#pragma unroll
    for (int c = 0; c < 2; ++c)
      acc[a][c] = (f32x4){0.f, 0.f, 0.f, 0.f};

  const uint4* w2f4 = (const uint4*)w2f;
  for (int ks = 0; ks < 17; ++ks) {
    union { uint4 q; bf16x8 v; } A[2], B[8];
#pragma unroll
    for (int ci = 0; ci < 2; ++ci)
      A[ci].q = w2f4[(ks * 16 + wv * 2 + ci) * 64 + lane];
#pragma unroll
    for (int pt = 0; pt < 8; ++pt) {
      const unsigned short* src = &pk[(pt * 16 + l15) * 548 + ks * 32 + l4 * 8];
      uint2 lo = *(const uint2*)src;
      uint2 hi = *(const uint2*)(src + 4);
      B[pt].q = make_uint4(lo.x, lo.y, hi.x, hi.y);
    }
#pragma unroll
    for (int pt = 0; pt < 8; ++pt)
#pragma unroll
      for (int ci = 0; ci < 2; ++ci)
        acc[pt][ci] = __builtin_amdgcn_mfma_f32_16x16x32_bf16(
            A[ci].v, B[pt].v, acc[pt][ci], 0, 0, 0);
  }

  // ---- epilogue: BN fold + relu, coalesced stores
#pragma unroll
  for (int pt = 0; pt < 8; ++pt) {
    int hw = hw0 + pt * 16 + l15;
#pragma unroll
    for (int ci = 0; ci < 2; ++ci) {
      int ch = (wv * 2 + ci) * 16 + l4 * 4;
#pragma unroll
      for (int r = 0; r < 4; ++r) {
        float v = fmaxf(acc[pt][ci][r] + bet[ci][r], 0.f);
        out[(((size_t)b * 256 + (ch + r)) << 12) + hw] = v;
      }
    }
  }
}

// ---------------------------------------------------------------------------
extern "C" void kernel_launch(void* const* d_in, const int* in_sizes, int n_in,
                              void* d_out, int out_size, void* d_ws, size_t ws_size,
                              hipStream_t stream)
{
  const float* x   = (const float*)d_in[0];
  const float* w1  = (const float*)d_in[1];
  const float* b1  = (const float*)d_in[2];
  const float* g1  = (const float*)d_in[3];
  const float* be1 = (const float*)d_in[4];
  const float* m1  = (const float*)d_in[5];
  const float* v1  = (const float*)d_in[6];
  const float* w2  = (const float*)d_in[7];
  const float* b2  = (const float*)d_in[8];
  const float* g2  = (const float*)d_in[9];
  const float* be2 = (const float*)d_in[10];
  const float* m2  = (const float*)d_in[11];
  const float* v2  = (const float*)d_in[12];

  char* ws = (char*)d_ws;
  float*          beta1 = (float*)(ws);                   // 128 B
  float*          beta2 = (float*)(ws + 128);             // 1024 B
  unsigned short* w1b   = (unsigned short*)(ws + 1152);   // 16384 B
  unsigned short* w2f   = (unsigned short*)(ws + 17536);  // 278528 B
  unsigned short* yws   = (unsigned short*)(ws + 296064); // 4 MB
  float* out = (float*)d_out;

  k_prep<<<dim3(544), dim3(256), 0, stream>>>(
      w1, b1, g1, be1, m1, v1, w2, b2, g2, be2, m2, v2, beta1, beta2, w1b, w2f);
  k_l1<<<dim3(2048), dim3(256), 0, stream>>>(x, w1b, beta1, yws);
  k_l2<<<dim3(512), dim3(512), 0, stream>>>(yws, w2f, beta2, out);
}